// Round 1
// baseline (325.223 us; speedup 1.0000x reference)
//
#include <hip/hip_runtime.h>
#include <hip/hip_bf16.h>
#include <stdint.h>

#define B_N 2
#define S_N 2048
#define D_N 1024
#define H_N 16

using bf8   = __attribute__((ext_vector_type(8))) short;   // 8 bf16 (4 VGPRs)
using f32x4 = __attribute__((ext_vector_type(4))) float;

static __device__ __forceinline__ ushort f2b(float f) {
  uint32_t u = __builtin_bit_cast(uint32_t, f);
  u += 0x7fffu + ((u >> 16) & 1u);     // RNE
  return (ushort)(u >> 16);
}

__global__ __launch_bounds__(256) void cvt_kernel(const float* __restrict__ s,
                                                  ushort* __restrict__ d, int n) {
  int i = (blockIdx.x * 256 + threadIdx.x) * 4;
  if (i >= n) return;
  float4 v = *(const float4*)(s + i);
  ushort4 o;
  o.x = f2b(v.x); o.y = f2b(v.y); o.z = f2b(v.z); o.w = f2b(v.w);
  *(ushort4*)(d + i) = o;
}

__global__ __launch_bounds__(256) void pack_codes_kernel(
    const int* __restrict__ f, const int* __restrict__ e, const int* __restrict__ ti,
    const int* __restrict__ tt, const int* __restrict__ ed, const int* __restrict__ ro,
    uint32_t* __restrict__ codes, int n) {
  int i = blockIdx.x * 256 + threadIdx.x;
  if (i >= n) return;
  uint32_t c = ((uint32_t)f[i] & 31u) | (((uint32_t)e[i] & 63u) << 5) |
               (((uint32_t)ti[i] & 127u) << 11) | (((uint32_t)tt[i] & 7u) << 18) |
               (((uint32_t)ro[i] & 7u) << 21) |
               ((ed[i] != 0) ? (1u << 24) : 0u) | ((f[i] == 0) ? (1u << 25) : 0u);
  codes[i] = c;
}

// bias(i,j) from packed codes; pad -> -1e30
static __device__ __forceinline__ float bias_f(uint32_t a, uint32_t b) {
  uint32_t x = a ^ b;
  uint32_t o = a | b;
  float v = (o & 0x1000000u) ? 1.5f : 0.0f;   // has_edge
  v += (x & 0x1Fu)     ? 0.0f : 1.0f;          // field
  v += (x & 0x7E0u)    ? 0.0f : 1.0f;          // entity
  v += (x & 0x3F800u)  ? 0.0f : 0.5f;          // time
  v += (x & 0x1C0000u) ? 0.0f : 0.3f;          // token_type
  v += (x & 0xE00000u) ? 0.0f : 0.5f;          // role
  return (o & 0x2000000u) ? -1e30f : v;        // pad mask
}

// C[M,N] = A[M,K] @ B[N,K]^T + bias  (A,B bf16; MODE 0: bf16 scatter to [B,H,S,64], MODE 1: f32 [M,N])
template <int MODE>
__global__ __launch_bounds__(256) void gemm_bt(const ushort* __restrict__ A, const ushort* __restrict__ Bw,
                                               const float* __restrict__ bias, void* __restrict__ Cout,
                                               int M, int N, int K, float scale) {
  __shared__ __align__(16) ushort As[128 * 32];
  __shared__ __align__(16) ushort Bs[64 * 32];
  const int tid  = threadIdx.x;
  const int lane = tid & 63;
  const int wid  = tid >> 6;
  const int g = lane >> 4, c = lane & 15;
  const int wm = wid >> 1, wn = wid & 1;
  const int m0 = blockIdx.y * 128, n0 = blockIdx.x * 64;

  f32x4 acc[4][2];
#pragma unroll
  for (int i = 0; i < 4; ++i)
#pragma unroll
    for (int j = 0; j < 2; ++j) acc[i][j] = (f32x4){0.f, 0.f, 0.f, 0.f};

  for (int k0 = 0; k0 < K; k0 += 32) {
    // stage A (128x32) + B (64x32) as 16B chunks, XOR-swizzled 16B slots
#pragma unroll
    for (int j = 0; j < 2; ++j) {
      int idx = tid + j * 256;
      int row = idx >> 2, slot = idx & 3;
      uint4 v = *(const uint4*)(A + (size_t)(m0 + row) * K + k0 + slot * 8);
      *(uint4*)(As + row * 32 + ((slot ^ (row & 3)) * 8)) = v;
    }
    {
      int row = tid >> 2, slot = tid & 3;
      uint4 v = *(const uint4*)(Bw + (size_t)(n0 + row) * K + k0 + slot * 8);
      *(uint4*)(Bs + row * 32 + ((slot ^ (row & 3)) * 8)) = v;
    }
    __syncthreads();
    bf8 af[4], bf_[2];
#pragma unroll
    for (int mi = 0; mi < 4; ++mi) {
      int row = wm * 64 + mi * 16 + c;
      af[mi] = *(const bf8*)(As + row * 32 + ((g ^ (row & 3)) * 8));
    }
#pragma unroll
    for (int ni = 0; ni < 2; ++ni) {
      int row = wn * 32 + ni * 16 + c;
      bf_[ni] = *(const bf8*)(Bs + row * 32 + ((g ^ (row & 3)) * 8));
    }
#pragma unroll
    for (int mi = 0; mi < 4; ++mi)
#pragma unroll
      for (int ni = 0; ni < 2; ++ni)
        acc[mi][ni] = __builtin_amdgcn_mfma_f32_16x16x32_bf16(af[mi], bf_[ni], acc[mi][ni], 0, 0, 0);
    __syncthreads();
  }

#pragma unroll
  for (int mi = 0; mi < 4; ++mi)
#pragma unroll
    for (int ni = 0; ni < 2; ++ni) {
      int ncol = n0 + wn * 32 + ni * 16 + c;
      float bv = bias[ncol];
#pragma unroll
      for (int r = 0; r < 4; ++r) {
        int m = m0 + wm * 64 + mi * 16 + g * 4 + r;
        float v = (acc[mi][ni][r] + bv) * scale;
        if (MODE == 0) {
          int bb = m >> 11, s = m & 2047;
          int hh = ncol >> 6, dd = ncol & 63;
          ((ushort*)Cout)[(((size_t)bb * H_N + hh) * S_N + s) * 64 + dd] = f2b(v);
        } else {
          ((float*)Cout)[(size_t)m * N + ncol] = v;
        }
      }
    }
}

// [B,H,S,64] -> [B,H,64,S]
__global__ __launch_bounds__(256) void transpose_v(const ushort* __restrict__ Vw, ushort* __restrict__ VT) {
  __shared__ __align__(16) ushort t[64 * 72];
  const int bh = blockIdx.y;
  const int s0 = blockIdx.x * 64;
  const int tid = threadIdx.x;
#pragma unroll
  for (int j = 0; j < 2; ++j) {
    int idx = tid + j * 256;
    int s = idx >> 3, d0 = (idx & 7) * 8;
    uint4 v = *(const uint4*)(Vw + ((size_t)bh * S_N + s0 + s) * 64 + d0);
    *(uint4*)(t + s * 72 + d0) = v;
  }
  __syncthreads();
#pragma unroll
  for (int j = 0; j < 2; ++j) {
    int idx = tid + j * 256;
    int d = idx >> 3, k0 = (idx & 7) * 8;
    uint32_t rr[4];
#pragma unroll
    for (int p = 0; p < 4; ++p)
      rr[p] = (uint32_t)t[(k0 + 2 * p) * 72 + d] | ((uint32_t)t[(k0 + 2 * p + 1) * 72 + d] << 16);
    uint4 ov; ov.x = rr[0]; ov.y = rr[1]; ov.z = rr[2]; ov.w = rr[3];
    *(uint4*)(VT + ((size_t)bh * 64 + d) * S_N + s0 + k0) = ov;
  }
}

// Flash attention with on-the-fly structural bias.
// grid (S/64, B*H), 256 thr (4 waves x 16 q rows). Q pre-scaled by 0.125 at projection.
__global__ __launch_bounds__(256) void attn_kernel(const ushort* __restrict__ Qw, const ushort* __restrict__ Kw,
                                                   const ushort* __restrict__ VT, const uint32_t* __restrict__ codes,
                                                   ushort* __restrict__ AO) {
  __shared__ __align__(16) ushort Ks[64 * 64];
  __shared__ __align__(16) ushort Vs[64 * 64];   // V^T tile: [hd][key]
  __shared__ __align__(16) ushort Ps[4][16 * 64];
  __shared__ uint32_t cs[64];
  const int tid = threadIdx.x, lane = tid & 63, wid = tid >> 6;
  const int g = lane >> 4, c = lane & 15;
  const int bh = blockIdx.y, b = bh >> 4;
  const int q0 = blockIdx.x * 64;

  bf8 aq[2];
  {
    const ushort* qp = Qw + ((size_t)bh * S_N + q0 + wid * 16 + c) * 64;
    aq[0] = *(const bf8*)(qp + g * 8);
    aq[1] = *(const bf8*)(qp + 32 + g * 8);
  }
  uint32_t cq[4];
#pragma unroll
  for (int r = 0; r < 4; ++r) cq[r] = codes[b * S_N + q0 + wid * 16 + g * 4 + r];

  float mr[4], lr[4];
  f32x4 o[4];
#pragma unroll
  for (int r = 0; r < 4; ++r) { mr[r] = -1e30f; lr[r] = 0.f; }
#pragma unroll
  for (int t = 0; t < 4; ++t) o[t] = (f32x4){0.f, 0.f, 0.f, 0.f};

  for (int kv0 = 0; kv0 < S_N; kv0 += 64) {
#pragma unroll
    for (int j = 0; j < 2; ++j) {
      int idx = tid + j * 256;
      int row = idx >> 3, slot = idx & 7;
      uint4 kvv = *(const uint4*)(Kw + ((size_t)bh * S_N + kv0 + row) * 64 + slot * 8);
      *(uint4*)(Ks + row * 64 + ((slot ^ (row & 7)) * 8)) = kvv;
      uint4 vvv = *(const uint4*)(VT + ((size_t)bh * 64 + row) * S_N + kv0 + slot * 8);
      *(uint4*)(Vs + row * 64 + ((slot ^ (row & 7)) * 8)) = vvv;
    }
    if (tid < 64) cs[tid] = codes[b * S_N + kv0 + tid];
    __syncthreads();

    uint32_t ck[4];
#pragma unroll
    for (int t = 0; t < 4; ++t) ck[t] = cs[t * 16 + c];

    // scores: acc initialized with structural bias, Q already carries 1/sqrt(64)
    f32x4 s[4];
#pragma unroll
    for (int t = 0; t < 4; ++t) {
#pragma unroll
      for (int r = 0; r < 4; ++r) s[t][r] = bias_f(cq[r], ck[t]);
    }
#pragma unroll
    for (int t = 0; t < 4; ++t) {
      int row = t * 16 + c;
#pragma unroll
      for (int kk = 0; kk < 2; ++kk) {
        bf8 kb = *(const bf8*)(Ks + row * 64 + (((kk * 4 + g) ^ (row & 7)) * 8));
        s[t] = __builtin_amdgcn_mfma_f32_16x16x32_bf16(aq[kk], kb, s[t], 0, 0, 0);
      }
    }

    // online softmax (rows = g*4+r, 16 cols per tile across lanes' c)
    float mn[4], sc[4];
#pragma unroll
    for (int r = 0; r < 4; ++r) {
      float v = fmaxf(fmaxf(s[0][r], s[1][r]), fmaxf(s[2][r], s[3][r]));
      v = fmaxf(v, __shfl_xor(v, 1));
      v = fmaxf(v, __shfl_xor(v, 2));
      v = fmaxf(v, __shfl_xor(v, 4));
      v = fmaxf(v, __shfl_xor(v, 8));
      mn[r] = fmaxf(mr[r], v);
      sc[r] = __expf(mr[r] - mn[r]);
      mr[r] = mn[r];
    }
#pragma unroll
    for (int r = 0; r < 4; ++r) {
      float a0 = 0.f;
#pragma unroll
      for (int t = 0; t < 4; ++t) { s[t][r] = __expf(s[t][r] - mn[r]); a0 += s[t][r]; }
      a0 += __shfl_xor(a0, 1);
      a0 += __shfl_xor(a0, 2);
      a0 += __shfl_xor(a0, 4);
      a0 += __shfl_xor(a0, 8);
      lr[r] = lr[r] * sc[r] + a0;
#pragma unroll
      for (int t = 0; t < 4; ++t) o[t][r] *= sc[r];
    }

    // P -> per-wave LDS (swizzled), read back as MFMA A fragments
    ushort* P = &Ps[wid][0];
#pragma unroll
    for (int t = 0; t < 4; ++t) {
#pragma unroll
      for (int r = 0; r < 4; ++r) {
        int row = g * 4 + r, col = t * 16 + c;
        P[(row * 128 + ((col * 2) ^ ((row & 7) << 4))) >> 1] = f2b(s[t][r]);
      }
    }
    bf8 pa[2];
#pragma unroll
    for (int kk = 0; kk < 2; ++kk)
      pa[kk] = *(const bf8*)((const char*)P + c * 128 + (((kk * 4 + g) ^ (c & 7)) * 16));
#pragma unroll
    for (int t = 0; t < 4; ++t) {
      int row = t * 16 + c;
#pragma unroll
      for (int kk = 0; kk < 2; ++kk) {
        bf8 vb = *(const bf8*)(Vs + row * 64 + (((kk * 4 + g) ^ (row & 7)) * 8));
        o[t] = __builtin_amdgcn_mfma_f32_16x16x32_bf16(pa[kk], vb, o[t], 0, 0, 0);
      }
    }
    __syncthreads();
  }

#pragma unroll
  for (int t = 0; t < 4; ++t) {
    int ncol = (bh & 15) * 64 + t * 16 + c;
#pragma unroll
    for (int r = 0; r < 4; ++r) {
      int qrow = q0 + wid * 16 + g * 4 + r;
      float v = o[t][r] / lr[r];
      AO[((size_t)b * S_N + qrow) * D_N + ncol] = f2b(v);
    }
  }
}

extern "C" void kernel_launch(void* const* d_in, const int* in_sizes, int n_in,
                              void* d_out, int out_size, void* d_ws, size_t ws_size,
                              hipStream_t stream) {
  (void)in_sizes; (void)n_in; (void)out_size; (void)ws_size;
  const float* query = (const float*)d_in[0];
  const float* key_  = (const float*)d_in[1];
  const float* value = (const float*)d_in[2];
  const int* fid  = (const int*)d_in[3];
  const int* eid  = (const int*)d_in[4];
  const int* tmid = (const int*)d_in[5];
  const int* ttid = (const int*)d_in[6];
  const int* edid = (const int*)d_in[7];
  const int* rlid = (const int*)d_in[8];
  const float* Wq = (const float*)d_in[9];  const float* bq = (const float*)d_in[10];
  const float* Wk = (const float*)d_in[11]; const float* bk = (const float*)d_in[12];
  const float* Wv = (const float*)d_in[13]; const float* bv = (const float*)d_in[14];
  const float* Wo = (const float*)d_in[15]; const float* bo = (const float*)d_in[16];

  char* ws = (char*)d_ws;
  const size_t SZ_X = (size_t)B_N * S_N * D_N * 2;  // 8 MB
  const size_t SZ_W = (size_t)D_N * D_N * 2;        // 2 MB
  ushort* Xq  = (ushort*)(ws);
  ushort* Xk  = (ushort*)(ws + SZ_X);
  ushort* Xv  = (ushort*)(ws + 2 * SZ_X);
  ushort* Wqb = (ushort*)(ws + 3 * SZ_X);
  ushort* Wkb = (ushort*)(ws + 3 * SZ_X + SZ_W);
  ushort* Wvb = (ushort*)(ws + 3 * SZ_X + 2 * SZ_W);
  ushort* Wob = (ushort*)(ws + 3 * SZ_X + 3 * SZ_W);
  ushort* Qws = (ushort*)(ws + 3 * SZ_X + 4 * SZ_W);
  ushort* Kws = (ushort*)(ws + 4 * SZ_X + 4 * SZ_W);
  ushort* Vws = (ushort*)(ws + 5 * SZ_X + 4 * SZ_W);
  ushort* VTw = (ushort*)(ws + 6 * SZ_X + 4 * SZ_W);
  ushort* AOw = (ushort*)(ws + 7 * SZ_X + 4 * SZ_W);
  uint32_t* codes = (uint32_t*)(ws + 8 * SZ_X + 4 * SZ_W);
  // total ws use: 8*SZ_X + 4*SZ_W + 16KB ~= 72.0 MB

  const int MK = B_N * S_N * D_N;
  const int WK = D_N * D_N;
  cvt_kernel<<<MK / 1024, 256, 0, stream>>>(query, Xq, MK);
  cvt_kernel<<<MK / 1024, 256, 0, stream>>>(key_, Xk, MK);
  cvt_kernel<<<MK / 1024, 256, 0, stream>>>(value, Xv, MK);
  cvt_kernel<<<WK / 1024, 256, 0, stream>>>(Wq, Wqb, WK);
  cvt_kernel<<<WK / 1024, 256, 0, stream>>>(Wk, Wkb, WK);
  cvt_kernel<<<WK / 1024, 256, 0, stream>>>(Wv, Wvb, WK);
  cvt_kernel<<<WK / 1024, 256, 0, stream>>>(Wo, Wob, WK);
  pack_codes_kernel<<<(B_N * S_N) / 256, 256, 0, stream>>>(fid, eid, tmid, ttid, edid, rlid, codes, B_N * S_N);

  dim3 gg(D_N / 64, (B_N * S_N) / 128);
  gemm_bt<0><<<gg, 256, 0, stream>>>(Xq, Wqb, bq, Qws, B_N * S_N, D_N, D_N, 0.125f);
  gemm_bt<0><<<gg, 256, 0, stream>>>(Xk, Wkb, bk, Kws, B_N * S_N, D_N, D_N, 1.0f);
  gemm_bt<0><<<gg, 256, 0, stream>>>(Xv, Wvb, bv, Vws, B_N * S_N, D_N, D_N, 1.0f);
  transpose_v<<<dim3(S_N / 64, B_N * H_N), 256, 0, stream>>>(Vws, VTw);
  attn_kernel<<<dim3(S_N / 64, B_N * H_N), 256, 0, stream>>>(Qws, Kws, VTw, codes, AOw);
  gemm_bt<1><<<gg, 256, 0, stream>>>(AOw, Wob, bo, d_out, B_N * S_N, D_N, D_N, 1.0f);
}

// Round 2
// 235.021 us; speedup vs baseline: 1.3838x; 1.3838x over previous
//
#include <hip/hip_runtime.h>
#include <hip/hip_bf16.h>
#include <stdint.h>

#define B_N 2
#define S_N 2048
#define D_N 1024
#define H_N 16

using bf8   = __attribute__((ext_vector_type(8))) short;   // 8 bf16 (4 VGPRs)
using f32x4 = __attribute__((ext_vector_type(4))) float;

static __device__ __forceinline__ ushort f2b(float f) {
  uint32_t u = __builtin_bit_cast(uint32_t, f);
  u += 0x7fffu + ((u >> 16) & 1u);     // RNE
  return (ushort)(u >> 16);
}

typedef __attribute__((address_space(1))) const uint32_t GU32;
typedef __attribute__((address_space(3))) uint32_t LU32;
static __device__ __forceinline__ void gload16(const void* g, void* l) {
  __builtin_amdgcn_global_load_lds((GU32*)g, (LU32*)l, 16, 0, 0);
}

// ---------------- f32 -> bf16 converts (fused) ----------------
__global__ __launch_bounds__(256) void cvt3_kernel(const float* __restrict__ a, const float* __restrict__ b,
                                                   const float* __restrict__ c, ushort* __restrict__ oa,
                                                   ushort* __restrict__ ob, ushort* __restrict__ oc) {
  const float* s; ushort* d;
  if (blockIdx.y == 0) { s = a; d = oa; }
  else if (blockIdx.y == 1) { s = b; d = ob; }
  else { s = c; d = oc; }
  int i = (blockIdx.x * 256 + threadIdx.x) * 4;
  float4 v = *(const float4*)(s + i);
  ushort4 o;
  o.x = f2b(v.x); o.y = f2b(v.y); o.z = f2b(v.z); o.w = f2b(v.w);
  *(ushort4*)(d + i) = o;
}

__global__ __launch_bounds__(256) void cvt4_kernel(const float* __restrict__ a, const float* __restrict__ b,
                                                   const float* __restrict__ c, const float* __restrict__ e,
                                                   ushort* __restrict__ oa, ushort* __restrict__ ob,
                                                   ushort* __restrict__ oc, ushort* __restrict__ oe) {
  const float* s; ushort* d;
  if (blockIdx.y == 0) { s = a; d = oa; }
  else if (blockIdx.y == 1) { s = b; d = ob; }
  else if (blockIdx.y == 2) { s = c; d = oc; }
  else { s = e; d = oe; }
  int i = (blockIdx.x * 256 + threadIdx.x) * 4;
  float4 v = *(const float4*)(s + i);
  ushort4 o;
  o.x = f2b(v.x); o.y = f2b(v.y); o.z = f2b(v.z); o.w = f2b(v.w);
  *(ushort4*)(d + i) = o;
}

// ---------------- structural-bias precompute ----------------
__global__ __launch_bounds__(256) void pack_codes_kernel(
    const int* __restrict__ f, const int* __restrict__ e, const int* __restrict__ ti,
    const int* __restrict__ tt, const int* __restrict__ ed, const int* __restrict__ ro,
    uint32_t* __restrict__ codes, int n) {
  int i = blockIdx.x * 256 + threadIdx.x;
  if (i >= n) return;
  uint32_t c = ((uint32_t)f[i] & 31u) | (((uint32_t)e[i] & 63u) << 5) |
               (((uint32_t)ti[i] & 127u) << 11) | (((uint32_t)tt[i] & 7u) << 18) |
               (((uint32_t)ro[i] & 7u) << 21) |
               ((ed[i] != 0) ? (1u << 24) : 0u) | ((f[i] == 0) ? (1u << 25) : 0u);
  codes[i] = c;
}

static __device__ __forceinline__ float bias_val(uint32_t a, uint32_t b) {
  uint32_t x = a ^ b;
  uint32_t o = a | b;
  float v = (o & 0x1000000u) ? 1.5f : 0.0f;   // has_edge
  v += (x & 0x1Fu)     ? 0.0f : 1.0f;          // field
  v += (x & 0x7E0u)    ? 0.0f : 1.0f;          // entity
  v += (x & 0x3F800u)  ? 0.0f : 0.5f;          // time
  v += (x & 0x1C0000u) ? 0.0f : 0.3f;          // token_type
  v += (x & 0xE00000u) ? 0.0f : 0.5f;          // role
  return (o & 0x2000000u) ? -30000.f : v;      // pad -> big negative (fp16-safe)
}

// BM[b][i][j] fp16, 8 elements per thread
__global__ __launch_bounds__(256) void bias_build(const uint32_t* __restrict__ codes,
                                                  ushort* __restrict__ BM) {
  int t = blockIdx.x * 256 + threadIdx.x;      // 0 .. B*S*S/8-1
  int j8 = (t & 255) * 8;                      // S/8 = 256
  int i  = (t >> 8) & 2047;
  int b  = t >> 19;                            // S*S/8 = 2^19
  uint32_t cq = codes[b * S_N + i];
  uint4 c0 = *(const uint4*)(codes + b * S_N + j8);
  uint4 c1 = *(const uint4*)(codes + b * S_N + j8 + 4);
  uint32_t cj[8] = {c0.x, c0.y, c0.z, c0.w, c1.x, c1.y, c1.z, c1.w};
  ushort o[8];
#pragma unroll
  for (int p = 0; p < 8; ++p) {
    _Float16 h = (_Float16)bias_val(cq, cj[p]);
    o[p] = __builtin_bit_cast(ushort, h);
  }
  *(uint4*)(BM + (size_t)t * 8) = *(const uint4*)o;
}

// ---------------- GEMM core: C[M,N] = A[M,K] @ W[N,K]^T + bias ----------------
// 128x128 tile, BK=32, 4 waves (2x2), 4x4 16x16 frags per wave, global_load_lds staging.
// MODE 0: bf16 scatter to [B,H,S,64]; MODE 1: f32 [M,N]; MODE 2: bf16 scatter-T to [B,H,64,S]
template <int MODE>
static __device__ __forceinline__ void gemm_core(ushort* As, ushort* Bs,
    const ushort* __restrict__ A, const ushort* __restrict__ W, const float* __restrict__ bias,
    void* __restrict__ out, float scale) {
  const int tid = threadIdx.x, lane = tid & 63, wid = tid >> 6;
  const int g = lane >> 4, c = lane & 15;
  const int wm = wid >> 1, wn = wid & 1;
  const int m0 = blockIdx.y * 128, n0 = blockIdx.x * 128;

  f32x4 acc[4][4];
#pragma unroll
  for (int i = 0; i < 4; ++i)
#pragma unroll
    for (int j = 0; j < 4; ++j) acc[i][j] = (f32x4){0.f, 0.f, 0.f, 0.f};

  for (int k0 = 0; k0 < D_N; k0 += 32) {
#pragma unroll
    for (int j = 0; j < 2; ++j) {
      int idx = tid + j * 256;                  // 0..511
      int row = idx >> 2, c8 = (idx & 3) * 8;
      gload16(A + (size_t)(m0 + row) * D_N + k0 + c8, As + idx * 8);
      gload16(W + (size_t)(n0 + row) * D_N + k0 + c8, Bs + idx * 8);
    }
    __syncthreads();
    bf8 af[4], bw[4];
#pragma unroll
    for (int mi = 0; mi < 4; ++mi) af[mi] = *(const bf8*)(As + (wm * 64 + mi * 16 + c) * 32 + g * 8);
#pragma unroll
    for (int ni = 0; ni < 4; ++ni) bw[ni] = *(const bf8*)(Bs + (wn * 64 + ni * 16 + c) * 32 + g * 8);
#pragma unroll
    for (int mi = 0; mi < 4; ++mi)
#pragma unroll
      for (int ni = 0; ni < 4; ++ni)
        acc[mi][ni] = __builtin_amdgcn_mfma_f32_16x16x32_bf16(af[mi], bw[ni], acc[mi][ni], 0, 0, 0);
    __syncthreads();
  }

#pragma unroll
  for (int mi = 0; mi < 4; ++mi)
#pragma unroll
    for (int ni = 0; ni < 4; ++ni) {
      int ncol = n0 + wn * 64 + ni * 16 + c;
      float bv = bias[ncol];
      int hh = ncol >> 6, dd = ncol & 63;
      if (MODE == 2) {
        int mb = m0 + wm * 64 + mi * 16 + g * 4;
        int bb = mb >> 11, s = mb & 2047;
        ushort4 o4;
        o4.x = f2b((acc[mi][ni][0] + bv) * scale);
        o4.y = f2b((acc[mi][ni][1] + bv) * scale);
        o4.z = f2b((acc[mi][ni][2] + bv) * scale);
        o4.w = f2b((acc[mi][ni][3] + bv) * scale);
        *(ushort4*)((ushort*)out + (((size_t)bb * H_N + hh) * 64 + dd) * S_N + s) = o4;
      } else {
#pragma unroll
        for (int r = 0; r < 4; ++r) {
          int m = m0 + wm * 64 + mi * 16 + g * 4 + r;
          float v = (acc[mi][ni][r] + bv) * scale;
          if (MODE == 0) {
            int bb = m >> 11, s = m & 2047;
            ((ushort*)out)[(((size_t)bb * H_N + hh) * S_N + s) * 64 + dd] = f2b(v);
          } else {
            ((float*)out)[(size_t)m * D_N + ncol] = v;
          }
        }
      }
    }
}

__global__ __launch_bounds__(256) void gemm_qkv(
    const ushort* __restrict__ Xq, const ushort* __restrict__ Xk, const ushort* __restrict__ Xv,
    const ushort* __restrict__ Wq, const ushort* __restrict__ Wk, const ushort* __restrict__ Wv,
    const float* __restrict__ bq, const float* __restrict__ bk, const float* __restrict__ bv,
    ushort* __restrict__ Qo, ushort* __restrict__ Ko, ushort* __restrict__ Vo) {
  __shared__ __align__(16) ushort As[128 * 32];
  __shared__ __align__(16) ushort Bs[128 * 32];
  if (blockIdx.z == 0)      gemm_core<0>(As, Bs, Xq, Wq, bq, Qo, 0.125f);
  else if (blockIdx.z == 1) gemm_core<0>(As, Bs, Xk, Wk, bk, Ko, 1.0f);
  else                      gemm_core<2>(As, Bs, Xv, Wv, bv, Vo, 1.0f);
}

__global__ __launch_bounds__(256) void gemm_o(const ushort* __restrict__ A, const ushort* __restrict__ W,
                                              const float* __restrict__ bias, float* __restrict__ out) {
  __shared__ __align__(16) ushort As[128 * 32];
  __shared__ __align__(16) ushort Bs[128 * 32];
  gemm_core<1>(As, Bs, A, W, bias, out, 1.0f);
}

// ---------------- flash attention with precomputed bias ----------------
// grid (S/64, B*H), 256 thr (4 waves x 16 q rows). Q pre-scaled by 0.125.
__global__ __launch_bounds__(256) void attn_kernel(const ushort* __restrict__ Qw, const ushort* __restrict__ Kw,
                                                   const ushort* __restrict__ VT, const ushort* __restrict__ BM,
                                                   ushort* __restrict__ AO) {
  __shared__ __align__(16) ushort Ks[64 * 64];
  __shared__ __align__(16) ushort Vs[64 * 64];   // V^T tile: [hd][key]
  __shared__ __align__(16) ushort Bts[64 * 72];  // bias tile [q][k] fp16, padded
  __shared__ __align__(16) ushort Ps[4][16 * 64];
  const int tid = threadIdx.x, lane = tid & 63, wid = tid >> 6;
  const int g = lane >> 4, c = lane & 15;
  const int bh = blockIdx.y, b = bh >> 4;
  const int q0 = blockIdx.x * 64;

  bf8 aq[2];
  {
    const ushort* qp = Qw + ((size_t)bh * S_N + q0 + wid * 16 + c) * 64;
    aq[0] = *(const bf8*)(qp + g * 8);
    aq[1] = *(const bf8*)(qp + 32 + g * 8);
  }
  // hoisted bias-read base addresses (per output row)
  const ushort* bp[4];
#pragma unroll
  for (int r = 0; r < 4; ++r) bp[r] = Bts + (wid * 16 + g * 4 + r) * 72 + c;

  float mr[4], lr[4];
  f32x4 o[4];
#pragma unroll
  for (int r = 0; r < 4; ++r) { mr[r] = -1e30f; lr[r] = 0.f; }
#pragma unroll
  for (int t = 0; t < 4; ++t) o[t] = (f32x4){0.f, 0.f, 0.f, 0.f};

  for (int kv0 = 0; kv0 < S_N; kv0 += 64) {
    // K/V: global_load_lds with pre-swizzled source (LDS layout == old swizzled layout)
#pragma unroll
    for (int j = 0; j < 2; ++j) {
      int idx = tid + j * 256;
      int row = idx >> 3, sl = ((idx & 7) ^ (row & 7)) * 8;
      gload16(Kw + ((size_t)bh * S_N + kv0 + row) * 64 + sl, Ks + idx * 8);
      gload16(VT + ((size_t)bh * 64 + row) * S_N + kv0 + sl, Vs + idx * 8);
    }
    // bias tile: reg-staged into padded [64][72]
#pragma unroll
    for (int j = 0; j < 2; ++j) {
      int idx = tid + j * 256;
      int rq = idx >> 3, c8 = (idx & 7) * 8;
      uint4 bvv = *(const uint4*)(BM + ((size_t)b * S_N + q0 + rq) * S_N + kv0 + c8);
      *(uint4*)(Bts + rq * 72 + c8) = bvv;
    }
    __syncthreads();

    // scores: acc initialized with bias tile (imm-offset ds_read_u16)
    f32x4 s[4];
#pragma unroll
    for (int t = 0; t < 4; ++t) {
#pragma unroll
      for (int r = 0; r < 4; ++r)
        s[t][r] = (float)*(const _Float16*)(bp[r] + t * 16);
    }
#pragma unroll
    for (int t = 0; t < 4; ++t) {
      int row = t * 16 + c;
#pragma unroll
      for (int kk = 0; kk < 2; ++kk) {
        bf8 kb = *(const bf8*)(Ks + row * 64 + (((kk * 4 + g) ^ (row & 7)) * 8));
        s[t] = __builtin_amdgcn_mfma_f32_16x16x32_bf16(aq[kk], kb, s[t], 0, 0, 0);
      }
    }

    // online softmax
    float mn[4], sc[4];
#pragma unroll
    for (int r = 0; r < 4; ++r) {
      float v = fmaxf(fmaxf(s[0][r], s[1][r]), fmaxf(s[2][r], s[3][r]));
      v = fmaxf(v, __shfl_xor(v, 1));
      v = fmaxf(v, __shfl_xor(v, 2));
      v = fmaxf(v, __shfl_xor(v, 4));
      v = fmaxf(v, __shfl_xor(v, 8));
      mn[r] = fmaxf(mr[r], v);
      sc[r] = __expf(mr[r] - mn[r]);
      mr[r] = mn[r];
    }
#pragma unroll
    for (int r = 0; r < 4; ++r) {
      float a0 = 0.f;
#pragma unroll
      for (int t = 0; t < 4; ++t) { s[t][r] = __expf(s[t][r] - mn[r]); a0 += s[t][r]; }
      a0 += __shfl_xor(a0, 1);
      a0 += __shfl_xor(a0, 2);
      a0 += __shfl_xor(a0, 4);
      a0 += __shfl_xor(a0, 8);
      lr[r] = lr[r] * sc[r] + a0;
#pragma unroll
      for (int t = 0; t < 4; ++t) o[t][r] *= sc[r];
    }

    // P -> per-wave LDS (swizzled), read back as MFMA A fragments
    ushort* P = &Ps[wid][0];
#pragma unroll
    for (int t = 0; t < 4; ++t) {
#pragma unroll
      for (int r = 0; r < 4; ++r) {
        int row = g * 4 + r, col = t * 16 + c;
        P[(row * 128 + ((col * 2) ^ ((row & 7) << 4))) >> 1] = f2b(s[t][r]);
      }
    }
    bf8 pa[2];
#pragma unroll
    for (int kk = 0; kk < 2; ++kk)
      pa[kk] = *(const bf8*)((const char*)P + c * 128 + (((kk * 4 + g) ^ (c & 7)) * 16));
#pragma unroll
    for (int t = 0; t < 4; ++t) {
      int row = t * 16 + c;
#pragma unroll
      for (int kk = 0; kk < 2; ++kk) {
        bf8 vb = *(const bf8*)(Vs + row * 64 + (((kk * 4 + g) ^ (row & 7)) * 8));
        o[t] = __builtin_amdgcn_mfma_f32_16x16x32_bf16(pa[kk], vb, o[t], 0, 0, 0);
      }
    }
    __syncthreads();
  }

#pragma unroll
  for (int t = 0; t < 4; ++t) {
    int ncol = (bh & 15) * 64 + t * 16 + c;
#pragma unroll
    for (int r = 0; r < 4; ++r) {
      int qrow = q0 + wid * 16 + g * 4 + r;
      float v = o[t][r] / lr[r];
      AO[((size_t)b * S_N + qrow) * D_N + ncol] = f2b(v);
    }
  }
}

extern "C" void kernel_launch(void* const* d_in, const int* in_sizes, int n_in,
                              void* d_out, int out_size, void* d_ws, size_t ws_size,
                              hipStream_t stream) {
  (void)in_sizes; (void)n_in; (void)out_size; (void)ws_size;
  const float* query = (const float*)d_in[0];
  const float* key_  = (const float*)d_in[1];
  const float* value = (const float*)d_in[2];
  const int* fid  = (const int*)d_in[3];
  const int* eid  = (const int*)d_in[4];
  const int* tmid = (const int*)d_in[5];
  const int* ttid = (const int*)d_in[6];
  const int* edid = (const int*)d_in[7];
  const int* rlid = (const int*)d_in[8];
  const float* Wq = (const float*)d_in[9];  const float* bq = (const float*)d_in[10];
  const float* Wk = (const float*)d_in[11]; const float* bk = (const float*)d_in[12];
  const float* Wv = (const float*)d_in[13]; const float* bv = (const float*)d_in[14];
  const float* Wo = (const float*)d_in[15]; const float* bo = (const float*)d_in[16];

  char* ws = (char*)d_ws;
  const size_t SZ_X = (size_t)B_N * S_N * D_N * 2;  // 8 MB
  const size_t SZ_W = (size_t)D_N * D_N * 2;        // 2 MB
  // [0,24MB): Xq/Xk/Xv during projections; reused as BM (16.8MB) afterwards
  ushort* Xq  = (ushort*)(ws);
  ushort* Xk  = (ushort*)(ws + SZ_X);
  ushort* Xv  = (ushort*)(ws + 2 * SZ_X);
  ushort* BM  = (ushort*)(ws);                      // bias matrix fp16 [B,S,S]
  ushort* Wqb = (ushort*)(ws + 3 * SZ_X);
  ushort* Wkb = (ushort*)(ws + 3 * SZ_X + SZ_W);
  ushort* Wvb = (ushort*)(ws + 3 * SZ_X + 2 * SZ_W);
  ushort* Wob = (ushort*)(ws + 3 * SZ_X + 3 * SZ_W);
  ushort* Qws = (ushort*)(ws + 3 * SZ_X + 4 * SZ_W);
  ushort* Kws = (ushort*)(ws + 4 * SZ_X + 4 * SZ_W);
  ushort* VTw = (ushort*)(ws + 5 * SZ_X + 4 * SZ_W);
  ushort* AOw = (ushort*)(ws + 6 * SZ_X + 4 * SZ_W);
  uint32_t* codes = (uint32_t*)(ws + 7 * SZ_X + 4 * SZ_W);
  // total ws: 7*8MB + 4*2MB + 16KB = 64.02 MB

  const int MK = B_N * S_N * D_N;
  const int WK = D_N * D_N;
  cvt3_kernel<<<dim3(MK / 1024, 3), 256, 0, stream>>>(query, key_, value, Xq, Xk, Xv);
  cvt4_kernel<<<dim3(WK / 1024, 4), 256, 0, stream>>>(Wq, Wk, Wv, Wo, Wqb, Wkb, Wvb, Wob);
  pack_codes_kernel<<<(B_N * S_N) / 256, 256, 0, stream>>>(fid, eid, tmid, ttid, edid, rlid, codes, B_N * S_N);

  gemm_qkv<<<dim3(D_N / 128, (B_N * S_N) / 128, 3), 256, 0, stream>>>(
      Xq, Xk, Xv, Wqb, Wkb, Wvb, bq, bk, bv, Qws, Kws, VTw);
  // bias matrix overwrites Xq/Xk/Xv region (dead after gemm_qkv)
  bias_build<<<(B_N * S_N * S_N / 8) / 256, 256, 0, stream>>>(codes, BM);
  attn_kernel<<<dim3(S_N / 64, B_N * H_N), 256, 0, stream>>>(Qws, Kws, VTw, BM, AOw);
  gemm_o<<<dim3(D_N / 128, (B_N * S_N) / 128), 256, 0, stream>>>(AOw, Wob, bo, (float*)d_out);
}